// Round 9
// baseline (306.928 us; speedup 1.0000x reference)
//
#include <hip/hip_runtime.h>
#include <hip/hip_bf16.h>
#include <stdint.h>

typedef __bf16 bf16;
typedef __attribute__((ext_vector_type(8))) __bf16 bf16x8;
typedef __attribute__((ext_vector_type(4))) float f32x4;
typedef __attribute__((ext_vector_type(4))) unsigned int u32x4;

#define NH 16
#define DH 64
#define POOL 8
#define BATCH 4
#define SEQ 4096
#define DIMV 1024
#define QKV_N (3*DIMV)
#define M_TOTAL (BATCH*SEQ)
#define SCALE_F 0.125f
// pooled sums over 512 t; 1/512 and SCALE folded into W2 weights: exact.
#define AGS_F (SCALE_F / 512.0f)
#define BH (BATCH*NH)              // 64
#define TCH 16                     // t-split chunks for stage1
#define TCL (SEQ/TCH)              // 256 t per chunk
#define HP 128                     // h*p combined dim for P2/W2

#define AS1(p) ((const __attribute__((address_space(1))) void*)(p))
#define AS3(p) ((__attribute__((address_space(3))) void*)(p))
typedef const __attribute__((address_space(3))) char* lds_cp;

// ---------------- fused prep: x->bf16 convert + Wv / Wo transposes ----------
// R9: only the v-columns of Wqkv are transposed (q/k planes eliminated).
// block ranges: [0,8192) convert_x; [8192,9216) Wqkv-v; [9216,10240) Wo.
__global__ void prep(const float* __restrict__ x, bf16* __restrict__ xb,
                     const float* __restrict__ Wqkv, bf16* __restrict__ WqkvT,
                     const float* __restrict__ Wo, bf16* __restrict__ WoT) {
  __shared__ float tile[32][33];
  const int b = blockIdx.x;
  if (b < 8192) {
    size_t i = ((size_t)b * 256 + threadIdx.x) * 8;
    float4 f0 = *(const float4*)(x + i);
    float4 f1 = *(const float4*)(x + i + 4);
    bf16x8 o;
    o[0] = (bf16)f0.x; o[1] = (bf16)f0.y; o[2] = (bf16)f0.z; o[3] = (bf16)f0.w;
    o[4] = (bf16)f1.x; o[5] = (bf16)f1.y; o[6] = (bf16)f1.z; o[7] = (bf16)f1.w;
    *(bf16x8*)(xb + i) = o;
    return;
  }
  const float* in; bf16* out; int C, bx, by;
  if (b < 9216) { int bb = b - 8192; in = Wqkv; out = WqkvT; C = QKV_N; bx = 64 + (bb & 31); by = bb >> 5; }
  else          { int bb = b - 9216; in = Wo;   out = WoT;   C = DIMV;  bx = bb & 31;        by = bb >> 5; }
  const int R = DIMV;
  int c0 = bx * 32, r0 = by * 32;
  int tx = threadIdx.x & 31, ty = threadIdx.x >> 5;
  for (int i = ty; i < 32; i += 8)
    tile[i][tx] = in[(size_t)(r0 + i) * C + c0 + tx];
  __syncthreads();
  for (int i = ty; i < 32; i += 8)
    out[(size_t)(c0 + i) * R + r0 + tx] = (bf16)tile[tx][i];
}

// ---------------- pool_x: xpool[b*8+p][c] = sum over 512 t of xb ------------
// grid 256: bid>>3 = bucket (b*8+p), bid&7 = 64-row t-slice.  atomics fp32.
__global__ void pool_x(const bf16* __restrict__ xb, float* __restrict__ xpool) {
  const int bid = blockIdx.x;
  const int bucket = bid >> 3, slice = bid & 7;
  const int b = bucket >> 3, p = bucket & 7;
  const int tid = threadIdx.x;
  const int co = tid & 127;        // c-octet
  const int r0 = tid >> 7;         // 0..1
  const bf16* src = xb + ((size_t)b * SEQ + p * 512 + slice * 64 + r0) * DIMV + co * 8;
  float a[8] = {};
  for (int r = 0; r < 64; r += 2) {
    bf16x8 v = *(const bf16x8*)(src + (size_t)r * DIMV);
#pragma unroll
    for (int e = 0; e < 8; ++e) a[e] += (float)v[e];
  }
  float* dst = xpool + (size_t)bucket * DIMV + co * 8;
#pragma unroll
  for (int e = 0; e < 8; ++e) atomicAdd(&dst[e], a[e]);
}

// ---------------- agent_build: agent_s[bp][hd] = sum_c xpool[bp][c]*Wq[c][hd]
// (pool commutes with linear map: agent = pool(x) @ Wq, exact.)  fp32 weights.
// grid 128: bp = bid>>2, c-slice = bid&3 (256 c each); atomicAdd partials.
__global__ void agent_build(const float* __restrict__ xpool, const float* __restrict__ Wqkv,
                            float* __restrict__ agent_s) {
  __shared__ float xp[256];
  const int bid = blockIdx.x;
  const int bp = bid >> 2, cs = bid & 3;
  const int tid = threadIdx.x;
  xp[tid] = xpool[(size_t)bp * DIMV + cs * 256 + tid];
  __syncthreads();
  float acc[4] = {};
  const float* wbase = Wqkv + (size_t)(cs * 256) * QKV_N + tid * 4;  // q-cols [0,1024)
#pragma unroll 8
  for (int c = 0; c < 256; ++c) {
    float xv = xp[c];
    float4 wv = *(const float4*)(wbase + (size_t)c * QKV_N);
    acc[0] += xv * wv.x; acc[1] += xv * wv.y; acc[2] += xv * wv.z; acc[3] += xv * wv.w;
  }
  float* dst = agent_s + (size_t)bp * DIMV + tid * 4;
#pragma unroll
  for (int j = 0; j < 4; ++j) atomicAdd(&dst[j], acc[j]);
}

// ---------------- w2cat_build: score weights (dot-with-agent associativity) -
// scw[b][j][c] (bf16, j in [0,256)): j<128 -> q-scores, j>=128 -> k-scores.
// scw[b][qk*128+h*8+p][c] = AGS * sum_d Wqkv[c][qk*1024 + h*64+d] * agent_s[b*8+p][h*64+d]
// grid 512: ct=bid&3 (256-c chunk), qk=(bid>>2)&1, h=(bid>>3)&15, b=bid>>7.
__global__ void w2cat_build(const float* __restrict__ agent_s, const float* __restrict__ Wqkv,
                            bf16* __restrict__ scw) {
  __shared__ float ag[8][64];
  const int bid = blockIdx.x;
  const int ct = bid & 3, qk = (bid >> 2) & 1, h = (bid >> 3) & 15, b = bid >> 7;
  const int tid = threadIdx.x;
  for (int i = tid; i < 512; i += 256)
    ag[i >> 6][i & 63] = agent_s[(size_t)(b * 8 + (i >> 6)) * DIMV + h * 64 + (i & 63)];
  __syncthreads();
  const int c = ct * 256 + tid;
  const float* wrow = Wqkv + (size_t)c * QKV_N + qk * 1024 + h * 64;
  float wv[64];
#pragma unroll
  for (int d4 = 0; d4 < 16; ++d4) {
    float4 w4 = *(const float4*)(wrow + d4 * 4);
    wv[d4 * 4] = w4.x; wv[d4 * 4 + 1] = w4.y; wv[d4 * 4 + 2] = w4.z; wv[d4 * 4 + 3] = w4.w;
  }
#pragma unroll
  for (int p = 0; p < 8; ++p) {
    float s = 0.f;
#pragma unroll
    for (int d = 0; d < 64; ++d) s += wv[d] * ag[p][d];
    scw[((size_t)b * 256 + qk * 128 + h * 8 + p) * DIMV + c] = (bf16)(s * AGS_F);
  }
}

// ============================================================================
// vgemm: v = x @ Wv.  gemm1's R1-verified 256^2 8-phase structure, N=1024 ->
// grid 256 = exactly 1 round (vs old N=3072, 768 blocks, 107us).  Epilogue:
// v-plane scatter only (q/k planes and fused pooling eliminated by the
// associativity restructure).
// ============================================================================
__global__ __launch_bounds__(512, 2)
void vgemm(const bf16* __restrict__ A, const bf16* __restrict__ B,
           bf16* __restrict__ vOut) {
  constexpr int K1 = DIMV;       // 1024
  constexpr int NI = K1 / 128;   // 8 pipeline iterations (2 K-tiles each)

  __shared__ __align__(16) bf16 LA[2][2][8192];
  __shared__ __align__(16) bf16 LB[2][2][8192];

  const int tid  = threadIdx.x;
  const int w    = tid >> 6;
  const int lane = tid & 63;
  const int wm = (w >> 2) * 128;
  const int wn = (w & 3) * 64;

  // bijective XCD swizzle (256 % 8 == 0); 64 M-tiles x 4 N-tiles
  const int bid = blockIdx.x;
  const int swz = (bid & 7) * 32 + (bid >> 3);
  const int m0 = (swz >> 2) * 256;
  const int n0 = (swz & 3) * 256;

  const int rT  = tid >> 3;
  const int csT = (((tid & 7) ^ (rT & 7)) << 3);
  const bf16* Ag = A + (size_t)(m0 + rT) * K1 + csT;
  const bf16* Bg = B + (size_t)(n0 + rT) * K1 + csT;

  const int rA = lane & 15, C = lane >> 4, xr = rA & 7;
  const unsigned s0 = (unsigned)(((0 * 4 + C) ^ xr) << 4);
  const unsigned s1 = (unsigned)(((1 * 4 + C) ^ xr) << 4);
  const unsigned aoff = (unsigned)((wm + rA) << 7);
  const unsigned boff = (unsigned)((wn + rA) << 7);

  f32x4 acc[8][4] = {};
  u32x4 aR[4][2], bR[4][2];

#define STG(arr, Gp, half, kofs) do {                                         \
    const bf16* _s = (Gp) + (size_t)((half) * 128) * K1 + (kofs);             \
    char* _d = (char*)&arr[half][0] + (w << 10);                              \
    __builtin_amdgcn_global_load_lds(AS1(_s), AS3(_d), 16, 0, 0);             \
    __builtin_amdgcn_global_load_lds(AS1(_s + 64 * K1), AS3(_d + 8192), 16, 0, 0); \
  } while (0)

#define DSR0(d, p)    asm volatile("ds_read_b128 %0, %1" : "=v"(d) : "v"(p))
#define DSR(d, p, o)  asm volatile("ds_read_b128 %0, %1 offset:" o : "=v"(d) : "v"(p))

#define READS_A(LAb, qm) do {                                                 \
    lds_cp _p0 = (lds_cp)(const char*)&LAb[0][0] + aoff + s0 + (qm) * 8192;   \
    lds_cp _p1 = (lds_cp)(const char*)&LAb[0][0] + aoff + s1 + (qm) * 8192;   \
    DSR0(aR[0][0], _p0); DSR(aR[1][0], _p0, "2048");                          \
    DSR(aR[2][0], _p0, "4096"); DSR(aR[3][0], _p0, "6144");                   \
    DSR0(aR[0][1], _p1); DSR(aR[1][1], _p1, "2048");                          \
    DSR(aR[2][1], _p1, "4096"); DSR(aR[3][1], _p1, "6144");                   \
  } while (0)

#define READS_B01(LBb) do {                                                   \
    lds_cp _p0 = (lds_cp)(const char*)&LBb[0][0] + boff + s0;                 \
    lds_cp _p1 = (lds_cp)(const char*)&LBb[0][0] + boff + s1;                 \
    DSR0(bR[0][0], _p0); DSR(bR[1][0], _p0, "2048");                          \
    DSR0(bR[0][1], _p1); DSR(bR[1][1], _p1, "2048");                          \
  } while (0)

#define READS_B23(LBb) do {                                                   \
    lds_cp _p0 = (lds_cp)(const char*)&LBb[0][0] + boff + s0;                 \
    lds_cp _p1 = (lds_cp)(const char*)&LBb[0][0] + boff + s1;                 \
    DSR(bR[2][0], _p0, "4096"); DSR(bR[3][0], _p0, "6144");                   \
    DSR(bR[2][1], _p1, "4096"); DSR(bR[3][1], _p1, "6144");                   \
  } while (0)

#define WAITL8 do { asm volatile("s_waitcnt lgkmcnt(8)");                     \
                    __builtin_amdgcn_sched_barrier(0); } while (0)

#define MFMA_Q(qm, qn) do {                                                   \
    asm volatile("s_waitcnt lgkmcnt(0)");                                     \
    __builtin_amdgcn_sched_barrier(0);                                        \
    __builtin_amdgcn_s_setprio(1);                                            \
    _Pragma("unroll")                                                         \
    for (int il = 0; il < 4; ++il)                                            \
      _Pragma("unroll")                                                       \
      for (int jj = 0; jj < 2; ++jj) {                                        \
        f32x4& ac = acc[(qm) * 4 + il][(qn) * 2 + jj];                        \
        ac = __builtin_amdgcn_mfma_f32_16x16x32_bf16(                         \
            __builtin_bit_cast(bf16x8, aR[il][0]),                            \
            __builtin_bit_cast(bf16x8, bR[(qn) * 2 + jj][0]), ac, 0, 0, 0);   \
        ac = __builtin_amdgcn_mfma_f32_16x16x32_bf16(                         \
            __builtin_bit_cast(bf16x8, aR[il][1]),                            \
            __builtin_bit_cast(bf16x8, bR[(qn) * 2 + jj][1]), ac, 0, 0, 0);   \
      }                                                                       \
    __builtin_amdgcn_s_setprio(0);                                            \
    __builtin_amdgcn_sched_barrier(0);                                        \
  } while (0)

#define BAR __builtin_amdgcn_s_barrier()

  STG(LA[0], Ag, 0, 0); STG(LA[0], Ag, 1, 0);
  STG(LB[0], Bg, 0, 0); STG(LB[0], Bg, 1, 0);
  STG(LB[1], Bg, 0, 64); STG(LB[1], Bg, 1, 64);
  asm volatile("s_waitcnt vmcnt(4)");
  __builtin_amdgcn_sched_barrier(0);
  BAR;

  int kk = 0;
  for (int i = 0; i < NI - 1; ++i, kk += 128) {
    READS_A(LA[0], 0); READS_B01(LB[0]);
    STG(LA[1], Ag, 0, kk + 64);
    WAITL8;
    BAR; MFMA_Q(0, 0); BAR;
    READS_B23(LB[0]);
    STG(LA[1], Ag, 1, kk + 64);
    BAR; MFMA_Q(0, 1); BAR;
    READS_A(LA[0], 1);
    STG(LB[0], Bg, 0, kk + 128);
    BAR; MFMA_Q(1, 0); BAR;
    STG(LB[0], Bg, 1, kk + 128);
    BAR; MFMA_Q(1, 1);
    asm volatile("s_waitcnt vmcnt(4)");
    __builtin_amdgcn_sched_barrier(0);
    BAR;
    READS_A(LA[1], 0); READS_B01(LB[1]);
    STG(LA[0], Ag, 0, kk + 128);
    WAITL8;
    BAR; MFMA_Q(0, 0); BAR;
    READS_B23(LB[1]);
    STG(LA[0], Ag, 1, kk + 128);
    BAR; MFMA_Q(0, 1); BAR;
    READS_A(LA[1], 1);
    STG(LB[1], Bg, 0, kk + 192);
    BAR; MFMA_Q(1, 0); BAR;
    STG(LB[1], Bg, 1, kk + 192);
    BAR; MFMA_Q(1, 1);
    asm volatile("s_waitcnt vmcnt(4)");
    __builtin_amdgcn_sched_barrier(0);
    BAR;
  }
  READS_A(LA[0], 0); READS_B01(LB[0]);
  STG(LA[1], Ag, 0, kk + 64);
  WAITL8;
  BAR; MFMA_Q(0, 0); BAR;
  READS_B23(LB[0]);
  STG(LA[1], Ag, 1, kk + 64);
  BAR; MFMA_Q(0, 1); BAR;
  READS_A(LA[0], 1);
  BAR; MFMA_Q(1, 0); BAR;
  MFMA_Q(1, 1);
  asm volatile("s_waitcnt vmcnt(0)");
  __builtin_amdgcn_sched_barrier(0);
  BAR;
  READS_A(LA[1], 0); READS_B01(LB[1]);
  WAITL8;
  BAR; MFMA_Q(0, 0); BAR;
  READS_B23(LB[1]);
  BAR; MFMA_Q(0, 1); BAR;
  READS_A(LA[1], 1);
  BAR; MFMA_Q(1, 0); BAR;
  MFMA_Q(1, 1);

#undef STG
#undef DSR0
#undef DSR
#undef READS_A
#undef READS_B01
#undef READS_B23
#undef WAITL8
#undef MFMA_Q
#undef BAR

  // epilogue: v-plane scatter.  ncol in [0,1024) -> (head, d).
  const int cr = (lane >> 4) * 4;
  const int cc = lane & 15;
  const int ncol = n0 + wn;
  const int hh   = ncol >> 6;
  const int rowb = m0 + wm;
  const int bb_  = rowb >> 12;
  const int tb   = rowb & 4095;
  bf16* Cp = vOut + (size_t)(bb_ * NH + hh) * SEQ * DH;
#pragma unroll
  for (int i = 0; i < 8; ++i)
#pragma unroll
    for (int j = 0; j < 4; ++j)
#pragma unroll
      for (int r = 0; r < 4; ++r)
        Cp[(size_t)(tb + i * 16 + cr + r) * DH + (ncol & 63) + j * 16 + cc] = (bf16)acc[i][j][r];
}

// ============================================================================
// score_gemm: SC = x @ scw[b] (both q- and k-scores in one GEMM, N=256).
// R0-verified legacy 128^2 structure, K=1024.  Output scattered fp32 as
// SC[bh][t][qk*8+p] so attn_mid reads are 64B/thread fully coalesced.
// ============================================================================
__global__ __launch_bounds__(256)
void score_gemm(const bf16* __restrict__ A, const bf16* __restrict__ B,
                float* __restrict__ SC) {
  constexpr int K = DIMV;   // 1024
  __shared__ bf16 As[128 * 32];
  __shared__ bf16 Bs[128 * 32];
  const int tid  = threadIdx.x;
  const int w    = tid >> 6;
  const int lane = tid & 63;
  const int m0 = blockIdx.y * 128, n0 = blockIdx.x * 128;
  const int wm = (w & 1) * 64, wn = (w >> 1) * 64;

  const bf16* Bb = B + (size_t)(m0 >> 12) * 256 * K;   // per-batch score weights

  f32x4 acc[4][4] = {};

  const int g0  = w * 2;
  const int rig = lane >> 2;
  const int kcs = (lane & 3) ^ ((rig >> 1) & 3);
  const bf16* Ap0 = A + (size_t)(m0 + g0 * 16 + rig) * K + kcs * 8;
  const bf16* Ap1 = Ap0 + (size_t)16 * K;
  const bf16* Bp0 = Bb + (size_t)(n0 + g0 * 16 + rig) * K + kcs * 8;
  const bf16* Bp1 = Bp0 + (size_t)16 * K;
  bf16* AsW0 = As + g0 * 512;
  bf16* AsW1 = As + (g0 + 1) * 512;
  bf16* BsW0 = Bs + g0 * 512;
  bf16* BsW1 = Bs + (g0 + 1) * 512;

  for (int k0 = 0; k0 < K; k0 += 32) {
    __syncthreads();
    __builtin_amdgcn_global_load_lds(AS1(Ap0 + k0), AS3(AsW0), 16, 0, 0);
    __builtin_amdgcn_global_load_lds(AS1(Ap1 + k0), AS3(AsW1), 16, 0, 0);
    __builtin_amdgcn_global_load_lds(AS1(Bp0 + k0), AS3(BsW0), 16, 0, 0);
    __builtin_amdgcn_global_load_lds(AS1(Bp1 + k0), AS3(BsW1), 16, 0, 0);
    __syncthreads();

    bf16x8 a[4], b[4];
    const int C = lane >> 4;
#pragma unroll
    for (int i = 0; i < 4; ++i) {
      int ar = wm + i * 16 + (lane & 15);
      int sw = C ^ ((ar >> 1) & 3);
      a[i] = *(const bf16x8*)&As[ar * 32 + sw * 8];
    }
#pragma unroll
    for (int j = 0; j < 4; ++j) {
      int br = wn + j * 16 + (lane & 15);
      int sw = C ^ ((br >> 1) & 3);
      b[j] = *(const bf16x8*)&Bs[br * 32 + sw * 8];
    }
#pragma unroll
    for (int i = 0; i < 4; ++i)
#pragma unroll
      for (int j = 0; j < 4; ++j)
        acc[i][j] = __builtin_amdgcn_mfma_f32_16x16x32_bf16(a[i], b[j], acc[i][j], 0, 0, 0);
  }

  // epilogue: scatter fp32 scores -> SC[(b*16+h)][t][qk*8+p]
  const int cr = (lane >> 4) * 4;
  const int cc = lane & 15;
#pragma unroll
  for (int i = 0; i < 4; ++i) {
#pragma unroll
    for (int j = 0; j < 4; ++j) {
      int col = n0 + wn + j * 16 + cc;
      int qk = col >> 7, h = (col >> 3) & 15, p = col & 7;
#pragma unroll
      for (int r = 0; r < 4; ++r) {
        int row = m0 + wm + i * 16 + cr + r;
        int b = row >> 12, t = row & 4095;
        SC[((size_t)(b * NH + h) * SEQ + t) * 16 + qk * 8 + p] = acc[i][j][r];
      }
    }
  }
}

// ============================================================================
// attn_mid (R9): scores precomputed by score_gemm -> phase 1's q/k reads and
// dot loops deleted.  Thread t reads 16 fp32 (64B coalesced), does both
// softmaxes; phase 2 PV unchanged (R7-verified).
// ============================================================================
__global__ __launch_bounds__(256)
void attn_mid(const float* __restrict__ SC, const bf16* __restrict__ v,
              bf16* __restrict__ P2,
              float* __restrict__ pm, float* __restrict__ pl,
              float* __restrict__ pva) {
  const int tc = blockIdx.x, bh = blockIdx.y;
  const int tid = threadIdx.x;
  const int t0 = tc * TCL;

  __shared__ float se[TCL][9];
  __shared__ float rm[4][8], rl[4][8];

  const float* scp = SC + ((size_t)bh * SEQ + t0 + tid) * 16;
  float4 sq0 = *(const float4*)(scp);
  float4 sq1 = *(const float4*)(scp + 4);
  float4 sk0 = *(const float4*)(scp + 8);
  float4 sk1 = *(const float4*)(scp + 12);
  float scq[8] = {sq0.x, sq0.y, sq0.z, sq0.w, sq1.x, sq1.y, sq1.z, sq1.w};
  float sck[8] = {sk0.x, sk0.y, sk0.z, sk0.w, sk1.x, sk1.y, sk1.z, sk1.w};

  // P2: per-row softmax over p
  {
    float m = scq[0];
#pragma unroll
    for (int p = 1; p < 8; ++p) m = fmaxf(m, scq[p]);
    float wsum = 0.f, wgt[8];
#pragma unroll
    for (int p = 0; p < 8; ++p) { wgt[p] = __expf(scq[p] - m); wsum += wgt[p]; }
    float inv = 1.0f / wsum;
    int b = bh >> 4, h = bh & 15;
    bf16x8 o8;
#pragma unroll
    for (int p = 0; p < 8; ++p) o8[p] = (bf16)(wgt[p] * inv);
    *(bf16x8*)&P2[((size_t)(b * SEQ + t0 + tid)) * HP + h * 8] = o8;
  }

  // k path: chunk max
  float mx[8];
#pragma unroll
  for (int p = 0; p < 8; ++p) mx[p] = sck[p];
#pragma unroll
  for (int o = 32; o; o >>= 1)
#pragma unroll
    for (int p = 0; p < 8; ++p) mx[p] = fmaxf(mx[p], __shfl_xor(mx[p], o));
  if ((tid & 63) == 0)
#pragma unroll
    for (int p = 0; p < 8; ++p) rm[tid >> 6][p] = mx[p];
  __syncthreads();
  float m[8];
#pragma unroll
  for (int p = 0; p < 8; ++p)
    m[p] = fmaxf(fmaxf(rm[0][p], rm[1][p]), fmaxf(rm[2][p], rm[3][p]));

  float sl[8];
#pragma unroll
  for (int p = 0; p < 8; ++p) {
    float e = __expf(sck[p] - m[p]);
    se[tid][p] = e;
    sl[p] = e;
  }
#pragma unroll
  for (int o = 32; o; o >>= 1)
#pragma unroll
    for (int p = 0; p < 8; ++p) sl[p] += __shfl_xor(sl[p], o);
  if ((tid & 63) == 0)
#pragma unroll
    for (int p = 0; p < 8; ++p) rl[tid >> 6][p] = sl[p];
  __syncthreads();
  if (tid < 8) {
    float l = rl[0][tid] + rl[1][tid] + rl[2][tid] + rl[3][tid];
    pm[(size_t)(bh * TCH + tc) * 8 + tid] = m[tid];
    pl[(size_t)(bh * TCH + tc) * 8 + tid] = l;
  }
  __syncthreads();   // se complete for phase 2

  // phase 2: pva[p][d] = sum_t se[t][p]*v[t][d]
  const int lane = tid & 63;
  const int wv = tid >> 6;
  const int dg = lane & 7;
  const int to = lane >> 3;
  const int p0 = wv * 2;
  const bf16* vb = v + ((size_t)bh * SEQ + t0 + to) * DH + dg * 8;
  float a0[8] = {}, a1[8] = {};
  for (int tl = to; tl < TCL; tl += 8) {
    bf16x8 v8 = *(const bf16x8*)(vb + (size_t)(tl - to) * DH);
    float w0 = se[tl][p0];
    float w1 = se[tl][p0 + 1];
#pragma unroll
    for (int e = 0; e < 8; ++e) {
      float vf = (float)v8[e];
      a0[e] += w0 * vf;
      a1[e] += w1 * vf;
    }
  }
#pragma unroll
  for (int o = 8; o <= 32; o <<= 1) {
#pragma unroll
    for (int e = 0; e < 8; ++e) {
      a0[e] += __shfl_xor(a0[e], o);
      a1[e] += __shfl_xor(a1[e], o);
    }
  }
  if (to == 0) {
    float* o0 = pva + ((size_t)(bh * TCH + tc) * 8 + p0) * DH + dg * 8;
    float* o1 = o0 + DH;
#pragma unroll
    for (int e = 0; e < 8; ++e) { o0[e] = a0[e]; o1[e] = a1[e]; }
  }
}

// ---------------- combine chunk partials -> v_agent[bh][p][d] ----------------
__global__ void combine_vag(const float* __restrict__ pm, const float* __restrict__ pl,
                            const float* __restrict__ pva, float* __restrict__ vag) {
  int bh = blockIdx.x;
#pragma unroll
  for (int e = threadIdx.x; e < 512; e += 256) {
    int p = e >> 6, d = e & 63;
    float M = -1e30f;
#pragma unroll
    for (int tc = 0; tc < TCH; ++tc)
      M = fmaxf(M, pm[(size_t)(bh * TCH + tc) * 8 + p]);
    float L = 0.f, acc = 0.f;
#pragma unroll
    for (int tc = 0; tc < TCH; ++tc) {
      float w = __expf(pm[(size_t)(bh * TCH + tc) * 8 + p] - M);
      L   += w * pl[(size_t)(bh * TCH + tc) * 8 + p];
      acc += w * pva[((size_t)(bh * TCH + tc) * 8 + p) * DH + d];
    }
    vag[(size_t)bh * 512 + e] = acc / L;
  }
}

// ---- W2T[b][n][hp] = sum_d vag[b][hp][d] * WoT[n][h*64+d]  (bf16 out) ----
__global__ void w2_build(const float* __restrict__ vag, const bf16* __restrict__ WoT,
                         bf16* __restrict__ W2T) {
  int b = blockIdx.y;
  int n = blockIdx.x * 16 + (threadIdx.x & 15);
  int h = threadIdx.x >> 4;
  __shared__ float vg[128][65];
  for (int i = threadIdx.x; i < 128 * 64; i += 256)
    vg[i >> 6][i & 63] = vag[(size_t)b * 128 * 64 + i];
  __syncthreads();
  float acc[8] = {};
  const bf16* wrow = WoT + (size_t)n * DIMV + h * 64;
#pragma unroll
  for (int dv = 0; dv < 8; ++dv) {
    bf16x8 wv = *(const bf16x8*)(wrow + dv * 8);
#pragma unroll
    for (int e = 0; e < 8; ++e) {
      float wf = (float)wv[e];
      int d = dv * 8 + e;
#pragma unroll
      for (int p = 0; p < 8; ++p) acc[p] += vg[h * 8 + p][d] * wf;
    }
  }
  bf16x8 o;
#pragma unroll
  for (int p = 0; p < 8; ++p) o[p] = (bf16)acc[p];
  *(bf16x8*)&W2T[((size_t)b * DIMV + n) * HP + h * 8] = o;
}

// ============================================================================
// GEMM2: out = P2 @ W2T(batched)^T + bo.  256^2 tile, K=128 (R1-verified
// prologue+tail path).  Grid 256 = 1 block/CU.  (unchanged from R5)
// ============================================================================
__global__ __launch_bounds__(512, 2)
void gemm2_256(const bf16* __restrict__ A, const bf16* __restrict__ B,
               float* __restrict__ Out, const float* __restrict__ bias) {
  constexpr int K2 = HP;   // 128

  __shared__ __align__(16) bf16 LA[2][2][8192];
  __shared__ __align__(16) bf16 LB[2][2][8192];

  const int tid  = threadIdx.x;
  const int w    = tid >> 6;
  const int lane = tid & 63;
  const int wm = (w >> 2) * 128;
  const int wn = (w & 3) * 64;

  const int bid = blockIdx.x;
  const int swz = (bid & 7) * 32 + (bid >> 3);
  const int m0 = (swz >> 2) * 256;
  const int n0 = (swz & 3) * 256;

  const int rT  = tid >> 3;
  const int csT = (((tid & 7) ^ (rT & 7)) << 3);
  const bf16* Ag = A + (size_t)(m0 + rT) * K2 + csT;
  const bf16* Bg = B + ((size_t)(m0 >> 12) * DIMV + n0 + rT) * K2 + csT;

  const int rA = lane & 15, C = lane >> 4, xr = rA & 7;
  const unsigned s0 = (unsigned)(((0 * 4 + C) ^ xr) << 4);
  const unsigned s1 = (unsigned)(((1 * 4 + C) ^ xr) << 4);
  const unsigned aoff = (unsigned)((wm + rA) << 7);
  const unsigned boff = (unsigned)((wn + rA) << 7);

  f32x4 acc[8][4] = {};
  u32x4 aR[4][2], bR[4][2];

#define STG(arr, Gp, half, kofs) do {                                         \
    const bf16* _s = (Gp) + (size_t)((half) * 128) * K2 + (kofs);             \
    char* _d = (char*)&arr[half][0] + (w << 10);                              \
    __builtin_amdgcn_global_load_lds(AS1(_s), AS3(_d), 16, 0, 0);             \
    __builtin_amdgcn_global_load_lds(AS1(_s + 64 * K2), AS3(_d + 8192), 16, 0, 0); \
  } while (0)

#define DSR0(d, p)    asm volatile("ds_read_b128 %0, %1" : "=v"(d) : "v"(p))
#define DSR(d, p, o)  asm volatile("ds_read_b128 %0, %1 offset:" o : "=v"(d) : "v"(p))

#define READS_A(LAb, qm) do {                                                 \
    lds_cp _p0 = (lds_cp)(const char*)&LAb[0][0] + aoff + s0 + (qm) * 8192;   \
    lds_cp _p1 = (lds_cp)(const char*)&LAb[0][0] + aoff + s1 + (qm) * 8192;   \
    DSR0(aR[0][0], _p0); DSR(aR[1][0], _p0, "2048");                          \
    DSR(aR[2][0], _p0, "4096"); DSR(aR[3][0], _p0, "6144");                   \
    DSR0(aR[0][1], _p1); DSR(aR[1][1], _p1, "2048");                          \
    DSR(aR[2][1], _p1, "4096"); DSR(aR[3][1], _p1, "6144");                   \
  } while (0)

#define READS_B01(LBb) do {                                                   \
    lds_cp _p0 = (lds_cp)(const char*)&LBb[0][0] + boff + s0;                 \
    lds_cp _p1 = (lds_cp)(const char*)&LBb[0][0] + boff + s1;                 \
    DSR0(bR[0][0], _p0); DSR(bR[1][0], _p0, "2048");                          \
    DSR0(bR[0][1], _p1); DSR(bR[1][1], _p1, "2048");                          \
  } while (0)

#define READS_B23(LBb) do {                                                   \
    lds_cp _p0 = (lds_cp)(const char*)&LBb[0][0] + boff + s0;                 \
    lds_cp _p1 = (lds_cp)(const char*)&LBb[0][0] + boff + s1;                 \
    DSR(bR[2][0], _p0, "4096"); DSR(bR[3][0], _p0, "6144");                   \
    DSR(bR[2][1], _p1, "4096"); DSR(bR[3][1], _p1, "6144");                   \
  } while (0)

#define WAITL8 do { asm volatile("s_waitcnt lgkmcnt(8)");                     \
                    __builtin_amdgcn_sched_barrier(0); } while (0)

#define MFMA_Q(qm, qn) do {                                                   \
    asm volatile("s_waitcnt lgkmcnt(0)");                                     \
    __builtin_amdgcn_sched_barrier(0);                                        \
    __builtin_amdgcn_s_setprio(1);                                            \
    _Pragma("unroll")                                                         \
    for (int il = 0; il < 4; ++il)                                            \
      _Pragma("unroll")                                                       \
      for (int jj = 0; jj < 2; ++jj) {                                        \
        f32x4& ac = acc[(qm) * 4 + il][(qn) * 2 + jj];                        \
        ac = __builtin_amdgcn_mfma_f32_16x16x32_bf16(                         \
            __builtin_bit_cast(bf16x8, aR[il][0]),                            \
            __builtin_bit_cast(bf16x8, bR[(qn) * 2 + jj][0]), ac, 0, 0, 0);   \
        ac = __builtin_amdgcn_mfma_f32_16x16x32_bf16(                         \
            __builtin_bit_cast(bf16x8, aR[il][1]),                            \
            __builtin_bit_cast(bf16x8, bR[(qn) * 2 + jj][1]), ac, 0, 0, 0);   \
      }                                                                       \
    __builtin_amdgcn_s_setprio(0);                                            \
    __builtin_amdgcn_sched_barrier(0);                                        \
  } while (0)

#define BAR __builtin_amdgcn_s_barrier()

  STG(LA[0], Ag, 0, 0); STG(LA[0], Ag, 1, 0);
  STG(LB[0], Bg, 0, 0); STG(LB[0], Bg, 1, 0);
  STG(LB[1], Bg, 0, 64); STG(LB[1], Bg, 1, 64);
  asm volatile("s_waitcnt vmcnt(4)");
  __builtin_amdgcn_sched_barrier(0);
  BAR;

  READS_A(LA[0], 0); READS_B01(LB[0]);
  STG(LA[1], Ag, 0, 64);
  WAITL8;
  BAR; MFMA_Q(0, 0); BAR;
  READS_B23(LB[0]);
  STG(LA[1], Ag, 1, 64);
  BAR; MFMA_Q(0, 1); BAR;
  READS_A(LA[0], 1);
  BAR; MFMA_Q(1, 0); BAR;
  MFMA_Q(1, 1);
  asm volatile("s_waitcnt vmcnt(0)");
  __builtin_amdgcn_sched_barrier(0);
  BAR;
  READS_A(LA[1], 0); READS_B01(LB[1]);
  WAITL8;
  BAR; MFMA_Q(0, 0); BAR;
  READS_B23(LB[1]);
  BAR; MFMA_Q(0, 1); BAR;
  READS_A(LA[1], 1);
  BAR; MFMA_Q(1, 0); BAR;
  MFMA_Q(1, 1);

#undef STG
#undef DSR0
#undef DSR
#undef READS_A
#undef READS_B01
#undef READS_B23
#undef WAITL8
#undef MFMA_Q
#undef BAR

  const int cr = (lane >> 4) * 4;
  const int cc = lane & 15;
  const int rowb = m0 + wm;
  float bb4[4];
#pragma unroll
  for (int j = 0; j < 4; ++j) bb4[j] = bias[n0 + wn + j * 16 + cc];
#pragma unroll
  for (int i = 0; i < 8; ++i)
#pragma unroll
    for (int j = 0; j < 4; ++j) {
      const int col = n0 + wn + j * 16 + cc;
#pragma unroll
      for (int r = 0; r < 4; ++r)
        Out[(size_t)(rowb + i * 16 + cr + r) * DIMV + col] = acc[i][j][r] + bb4[j];
    }
}

extern "C" void kernel_launch(void* const* d_in, const int* in_sizes, int n_in,
                              void* d_out, int out_size, void* d_ws, size_t ws_size,
                              hipStream_t stream) {
  const float* x    = (const float*)d_in[0];   // [4,4096,1024] fp32
  const float* Wqkv = (const float*)d_in[1];   // [1024,3072]   fp32
  const float* Wo   = (const float*)d_in[2];   // [1024,1024]   fp32
  const float* bo   = (const float*)d_in[3];   // [1024]        fp32
  float* out = (float*)d_out;                  // [4,4096,1024] fp32

  char* ws = (char*)d_ws;
  bf16*  WqkvT  = (bf16*)ws;                                 ws += (size_t)QKV_N * DIMV * 2;   // 6MB (only v rows written)
  bf16*  WoT    = (bf16*)ws;                                 ws += (size_t)DIMV * DIMV * 2;    // 2MB
  bf16*  vpl    = (bf16*)ws;                                 ws += (size_t)BH * SEQ * DH * 2;  // 32MB v plane
  char*  wsu    = ws;                                        ws += (size_t)M_TOTAL * DIMV * 2; // 32MB
  bf16*  xb     = (bf16*)wsu;
  bf16*  P2     = (bf16*)wsu;                                 // 4MB (after xb dead)
  bf16*  W2T    = (bf16*)(wsu + (size_t)M_TOTAL * HP * 2);    // 1MB
  float* SC     = (float*)ws;                                ws += (size_t)BH * SEQ * 16 * 4;  // 16MB scores
  bf16*  scw    = (bf16*)ws;                                 ws += (size_t)BATCH * 256 * DIMV * 2; // 2MB
  float* xpool  = (float*)ws;                                ws += 32 * DIMV * 4;              // 128KB
  float* agent_s= (float*)ws;                                ws += 32 * DIMV * 4;              // 128KB
  float* pm     = (float*)ws;                                ws += BH * TCH * 8 * 4;
  float* pl     = (float*)ws;                                ws += BH * TCH * 8 * 4;
  float* pva    = (float*)ws;                                ws += (size_t)BH * TCH * 8 * DH * 4;
  float* vag    = (float*)ws;                                ws += 512 * 64 * 4;

  // atomically-accumulated buffers -> zero first
  hipMemsetAsync(xpool, 0, 32 * DIMV * 4, stream);
  hipMemsetAsync(agent_s, 0, 32 * DIMV * 4, stream);

  // prep: convert x (8192) + Wqkv v-cols transpose (1024) + Wo transpose (1024)
  prep<<<10240, 256, 0, stream>>>(x, xb, Wqkv, WqkvT, Wo, WoT);

  // agent from pooled x (pool commutes with linear map)
  pool_x<<<256, 256, 0, stream>>>(xb, xpool);
  agent_build<<<128, 256, 0, stream>>>(xpool, Wqkv, agent_s);
  w2cat_build<<<512, 256, 0, stream>>>(agent_s, Wqkv, scw);

  // v = x @ Wv (N=1024, 256 blocks = 1 round)
  vgemm<<<256, 512, 0, stream>>>(xb, WqkvT + (size_t)2048 * DIMV, vpl);

  // q- and k-scores in one GEMM: SC = x @ scw[b]  (N=256)
  score_gemm<<<dim3(2, 128), 256, 0, stream>>>(xb, scw, SC);

  // softmaxes + PV partials (P2 overwrites xb region AFTER xb's last use)
  attn_mid<<<dim3(TCH, BH), 256, 0, stream>>>(SC, vpl, P2, pm, pl, pva);

  combine_vag<<<BH, 256, 0, stream>>>(pm, pl, pva, vag);
  w2_build<<<dim3(DIMV / 16, BATCH), 256, 0, stream>>>(vag, WoT, W2T);

  // out = P2 @ W2T(batched) + bo
  gemm2_256<<<256, 512, 0, stream>>>(P2, W2T, out, bo);
}

// Round 10
// 302.886 us; speedup vs baseline: 1.0133x; 1.0133x over previous
//
#include <hip/hip_runtime.h>
#include <hip/hip_bf16.h>
#include <stdint.h>

typedef __bf16 bf16;
typedef __attribute__((ext_vector_type(8))) __bf16 bf16x8;
typedef __attribute__((ext_vector_type(4))) float f32x4;
typedef __attribute__((ext_vector_type(4))) unsigned int u32x4;

#define NH 16
#define DH 64
#define POOL 8
#define BATCH 4
#define SEQ 4096
#define DIMV 1024
#define QKV_N (3*DIMV)
#define M_TOTAL (BATCH*SEQ)
#define SCALE_F 0.125f
// pooled sums over 512 t; 1/512 and SCALE folded into W2 weights: exact.
#define AGS_F (SCALE_F / 512.0f)
#define BH (BATCH*NH)              // 64
#define TCH 16                     // t-split chunks for stage1
#define TCL (SEQ/TCH)              // 256 t per chunk
#define HP 128                     // h*p combined dim for P2/W2
#define SCPL ((size_t)BH*SEQ)      // score plane stride

#define AS1(p) ((const __attribute__((address_space(1))) void*)(p))
#define AS3(p) ((__attribute__((address_space(3))) void*)(p))
typedef const __attribute__((address_space(3))) char* lds_cp;

// ---------------- fused prep: x->bf16 convert + Wv / Wo transposes ----------
// block ranges: [0,8192) convert_x; [8192,9216) Wqkv-v; [9216,10240) Wo.
__global__ void prep(const float* __restrict__ x, bf16* __restrict__ xb,
                     const float* __restrict__ Wqkv, bf16* __restrict__ WqkvT,
                     const float* __restrict__ Wo, bf16* __restrict__ WoT) {
  __shared__ float tile[32][33];
  const int b = blockIdx.x;
  if (b < 8192) {
    size_t i = ((size_t)b * 256 + threadIdx.x) * 8;
    float4 f0 = *(const float4*)(x + i);
    float4 f1 = *(const float4*)(x + i + 4);
    bf16x8 o;
    o[0] = (bf16)f0.x; o[1] = (bf16)f0.y; o[2] = (bf16)f0.z; o[3] = (bf16)f0.w;
    o[4] = (bf16)f1.x; o[5] = (bf16)f1.y; o[6] = (bf16)f1.z; o[7] = (bf16)f1.w;
    *(bf16x8*)(xb + i) = o;
    return;
  }
  const float* in; bf16* out; int C, bx, by;
  if (b < 9216) { int bb = b - 8192; in = Wqkv; out = WqkvT; C = QKV_N; bx = 64 + (bb & 31); by = bb >> 5; }
  else          { int bb = b - 9216; in = Wo;   out = WoT;   C = DIMV;  bx = bb & 31;        by = bb >> 5; }
  const int R = DIMV;
  int c0 = bx * 32, r0 = by * 32;
  int tx = threadIdx.x & 31, ty = threadIdx.x >> 5;
  for (int i = ty; i < 32; i += 8)
    tile[i][tx] = in[(size_t)(r0 + i) * C + c0 + tx];
  __syncthreads();
  for (int i = ty; i < 32; i += 8)
    out[(size_t)(c0 + i) * R + r0 + tx] = (bf16)tile[tx][i];
}

// ---------------- pool_x: xpool[b*8+p][c] = sum over 512 t of xb ------------
__global__ void pool_x(const bf16* __restrict__ xb, float* __restrict__ xpool) {
  const int bid = blockIdx.x;
  const int bucket = bid >> 3, slice = bid & 7;
  const int b = bucket >> 3, p = bucket & 7;
  const int tid = threadIdx.x;
  const int co = tid & 127;
  const int r0 = tid >> 7;
  const bf16* src = xb + ((size_t)b * SEQ + p * 512 + slice * 64 + r0) * DIMV + co * 8;
  float a[8] = {};
  for (int r = 0; r < 64; r += 2) {
    bf16x8 v = *(const bf16x8*)(src + (size_t)r * DIMV);
#pragma unroll
    for (int e = 0; e < 8; ++e) a[e] += (float)v[e];
  }
  float* dst = xpool + (size_t)bucket * DIMV + co * 8;
#pragma unroll
  for (int e = 0; e < 8; ++e) atomicAdd(&dst[e], a[e]);
}

// ---------------- agent_build: agent_s[bp][hd] = sum_c xpool[bp][c]*Wq[c][hd]
__global__ void agent_build(const float* __restrict__ xpool, const float* __restrict__ Wqkv,
                            float* __restrict__ agent_s) {
  __shared__ float xp[256];
  const int bid = blockIdx.x;
  const int bp = bid >> 2, cs = bid & 3;
  const int tid = threadIdx.x;
  xp[tid] = xpool[(size_t)bp * DIMV + cs * 256 + tid];
  __syncthreads();
  float acc[4] = {};
  const float* wbase = Wqkv + (size_t)(cs * 256) * QKV_N + tid * 4;  // q-cols [0,1024)
#pragma unroll 8
  for (int c = 0; c < 256; ++c) {
    float xv = xp[c];
    float4 wv = *(const float4*)(wbase + (size_t)c * QKV_N);
    acc[0] += xv * wv.x; acc[1] += xv * wv.y; acc[2] += xv * wv.z; acc[3] += xv * wv.w;
  }
  float* dst = agent_s + (size_t)bp * DIMV + tid * 4;
#pragma unroll
  for (int j = 0; j < 4; ++j) atomicAdd(&dst[j], acc[j]);
}

// ---------------- w2cat_build: score weights (dot-with-agent associativity) -
// scw[b][j][c] (bf16, j in [0,256)): j<128 -> q-scores, j>=128 -> k-scores.
__global__ void w2cat_build(const float* __restrict__ agent_s, const float* __restrict__ Wqkv,
                            bf16* __restrict__ scw) {
  __shared__ float ag[8][64];
  const int bid = blockIdx.x;
  const int ct = bid & 3, qk = (bid >> 2) & 1, h = (bid >> 3) & 15, b = bid >> 7;
  const int tid = threadIdx.x;
  for (int i = tid; i < 512; i += 256)
    ag[i >> 6][i & 63] = agent_s[(size_t)(b * 8 + (i >> 6)) * DIMV + h * 64 + (i & 63)];
  __syncthreads();
  const int c = ct * 256 + tid;
  const float* wrow = Wqkv + (size_t)c * QKV_N + qk * 1024 + h * 64;
  float wv[64];
#pragma unroll
  for (int d4 = 0; d4 < 16; ++d4) {
    float4 w4 = *(const float4*)(wrow + d4 * 4);
    wv[d4 * 4] = w4.x; wv[d4 * 4 + 1] = w4.y; wv[d4 * 4 + 2] = w4.z; wv[d4 * 4 + 3] = w4.w;
  }
#pragma unroll
  for (int p = 0; p < 8; ++p) {
    float s = 0.f;
#pragma unroll
    for (int d = 0; d < 64; ++d) s += wv[d] * ag[p][d];
    scw[((size_t)b * 256 + qk * 128 + h * 8 + p) * DIMV + c] = (bf16)(s * AGS_F);
  }
}

// ============================================================================
// vscore_gemm: fused {v = x@Wv (256 v-tiles)} + {SC = x@scw[b] (64 score
// M-tiles, N=256)} -- one kernel, R1-verified 256^2 8-phase inner loop,
// block-uniform mode branch.  Grid 320 (%8==0, bijective XCD swizzle).
// SC stored in PLANE layout SC[qk*8+p][bh][t]: each lane float4-stores 4
// consecutive t; a wave covers 16 planes x one full 64B line -- fixes R9's
// 4B-at-64B-stride scatter (the suspected ~40us write-amplification).
// ============================================================================
__global__ __launch_bounds__(512, 2)
void vscore_gemm(const bf16* __restrict__ A, const bf16* __restrict__ Bv,
                 const bf16* __restrict__ scw,
                 bf16* __restrict__ vOut, float* __restrict__ SC) {
  constexpr int K1 = DIMV;       // 1024
  constexpr int NI = K1 / 128;

  __shared__ __align__(16) bf16 LA[2][2][8192];
  __shared__ __align__(16) bf16 LB[2][2][8192];

  const int tid  = threadIdx.x;
  const int w    = tid >> 6;
  const int lane = tid & 63;
  const int wm = (w >> 2) * 128;
  const int wn = (w & 3) * 64;

  // bijective XCD swizzle over 320 blocks; swz<64 -> score tile, else v tile
  const int bid = blockIdx.x;
  const int swz = (bid & 7) * 40 + (bid >> 3);
  const bool isScore = swz < 64;
  int m0, n0;
  const bf16* Bg0;
  if (isScore) {
    m0 = swz * 256; n0 = 0;
    Bg0 = scw + (size_t)(m0 >> 12) * 256 * K1;
  } else {
    const int vi = swz - 64;
    m0 = (vi >> 2) * 256; n0 = (vi & 3) * 256;
    Bg0 = Bv;
  }

  const int rT  = tid >> 3;
  const int csT = (((tid & 7) ^ (rT & 7)) << 3);
  const bf16* Ag = A + (size_t)(m0 + rT) * K1 + csT;
  const bf16* Bg = Bg0 + (size_t)(n0 + rT) * K1 + csT;

  const int rA = lane & 15, C = lane >> 4, xr = rA & 7;
  const unsigned s0 = (unsigned)(((0 * 4 + C) ^ xr) << 4);
  const unsigned s1 = (unsigned)(((1 * 4 + C) ^ xr) << 4);
  const unsigned aoff = (unsigned)((wm + rA) << 7);
  const unsigned boff = (unsigned)((wn + rA) << 7);

  f32x4 acc[8][4] = {};
  u32x4 aR[4][2], bR[4][2];

#define STG(arr, Gp, half, kofs) do {                                         \
    const bf16* _s = (Gp) + (size_t)((half) * 128) * K1 + (kofs);             \
    char* _d = (char*)&arr[half][0] + (w << 10);                              \
    __builtin_amdgcn_global_load_lds(AS1(_s), AS3(_d), 16, 0, 0);             \
    __builtin_amdgcn_global_load_lds(AS1(_s + 64 * K1), AS3(_d + 8192), 16, 0, 0); \
  } while (0)

#define DSR0(d, p)    asm volatile("ds_read_b128 %0, %1" : "=v"(d) : "v"(p))
#define DSR(d, p, o)  asm volatile("ds_read_b128 %0, %1 offset:" o : "=v"(d) : "v"(p))

#define READS_A(LAb, qm) do {                                                 \
    lds_cp _p0 = (lds_cp)(const char*)&LAb[0][0] + aoff + s0 + (qm) * 8192;   \
    lds_cp _p1 = (lds_cp)(const char*)&LAb[0][0] + aoff + s1 + (qm) * 8192;   \
    DSR0(aR[0][0], _p0); DSR(aR[1][0], _p0, "2048");                          \
    DSR(aR[2][0], _p0, "4096"); DSR(aR[3][0], _p0, "6144");                   \
    DSR0(aR[0][1], _p1); DSR(aR[1][1], _p1, "2048");                          \
    DSR(aR[2][1], _p1, "4096"); DSR(aR[3][1], _p1, "6144");                   \
  } while (0)

#define READS_B01(LBb) do {                                                   \
    lds_cp _p0 = (lds_cp)(const char*)&LBb[0][0] + boff + s0;                 \
    lds_cp _p1 = (lds_cp)(const char*)&LBb[0][0] + boff + s1;                 \
    DSR0(bR[0][0], _p0); DSR(bR[1][0], _p0, "2048");                          \
    DSR0(bR[0][1], _p1); DSR(bR[1][1], _p1, "2048");                          \
  } while (0)

#define READS_B23(LBb) do {                                                   \
    lds_cp _p0 = (lds_cp)(const char*)&LBb[0][0] + boff + s0;                 \
    lds_cp _p1 = (lds_cp)(const char*)&LBb[0][0] + boff + s1;                 \
    DSR(bR[2][0], _p0, "4096"); DSR(bR[3][0], _p0, "6144");                   \
    DSR(bR[2][1], _p1, "4096"); DSR(bR[3][1], _p1, "6144");                   \
  } while (0)

#define WAITL8 do { asm volatile("s_waitcnt lgkmcnt(8)");                     \
                    __builtin_amdgcn_sched_barrier(0); } while (0)

#define MFMA_Q(qm, qn) do {                                                   \
    asm volatile("s_waitcnt lgkmcnt(0)");                                     \
    __builtin_amdgcn_sched_barrier(0);                                        \
    __builtin_amdgcn_s_setprio(1);                                            \
    _Pragma("unroll")                                                         \
    for (int il = 0; il < 4; ++il)                                            \
      _Pragma("unroll")                                                       \
      for (int jj = 0; jj < 2; ++jj) {                                        \
        f32x4& ac = acc[(qm) * 4 + il][(qn) * 2 + jj];                        \
        ac = __builtin_amdgcn_mfma_f32_16x16x32_bf16(                         \
            __builtin_bit_cast(bf16x8, aR[il][0]),                            \
            __builtin_bit_cast(bf16x8, bR[(qn) * 2 + jj][0]), ac, 0, 0, 0);   \
        ac = __builtin_amdgcn_mfma_f32_16x16x32_bf16(                         \
            __builtin_bit_cast(bf16x8, aR[il][1]),                            \
            __builtin_bit_cast(bf16x8, bR[(qn) * 2 + jj][1]), ac, 0, 0, 0);   \
      }                                                                       \
    __builtin_amdgcn_s_setprio(0);                                            \
    __builtin_amdgcn_sched_barrier(0);                                        \
  } while (0)

#define BAR __builtin_amdgcn_s_barrier()

  STG(LA[0], Ag, 0, 0); STG(LA[0], Ag, 1, 0);
  STG(LB[0], Bg, 0, 0); STG(LB[0], Bg, 1, 0);
  STG(LB[1], Bg, 0, 64); STG(LB[1], Bg, 1, 64);
  asm volatile("s_waitcnt vmcnt(4)");
  __builtin_amdgcn_sched_barrier(0);
  BAR;

  int kk = 0;
  for (int i = 0; i < NI - 1; ++i, kk += 128) {
    READS_A(LA[0], 0); READS_B01(LB[0]);
    STG(LA[1], Ag, 0, kk + 64);
    WAITL8;
    BAR; MFMA_Q(0, 0); BAR;
    READS_B23(LB[0]);
    STG(LA[1], Ag, 1, kk + 64);
    BAR; MFMA_Q(0, 1); BAR;
    READS_A(LA[0], 1);
    STG(LB[0], Bg, 0, kk + 128);
    BAR; MFMA_Q(1, 0); BAR;
    STG(LB[0], Bg, 1, kk + 128);
    BAR; MFMA_Q(1, 1);
    asm volatile("s_waitcnt vmcnt(4)");
    __builtin_amdgcn_sched_barrier(0);
    BAR;
    READS_A(LA[1], 0); READS_B01(LB[1]);
    STG(LA[0], Ag, 0, kk + 128);
    WAITL8;
    BAR; MFMA_Q(0, 0); BAR;
    READS_B23(LB[1]);
    STG(LA[0], Ag, 1, kk + 128);
    BAR; MFMA_Q(0, 1); BAR;
    READS_A(LA[1], 1);
    STG(LB[1], Bg, 0, kk + 192);
    BAR; MFMA_Q(1, 0); BAR;
    STG(LB[1], Bg, 1, kk + 192);
    BAR; MFMA_Q(1, 1);
    asm volatile("s_waitcnt vmcnt(4)");
    __builtin_amdgcn_sched_barrier(0);
    BAR;
  }
  READS_A(LA[0], 0); READS_B01(LB[0]);
  STG(LA[1], Ag, 0, kk + 64);
  WAITL8;
  BAR; MFMA_Q(0, 0); BAR;
  READS_B23(LB[0]);
  STG(LA[1], Ag, 1, kk + 64);
  BAR; MFMA_Q(0, 1); BAR;
  READS_A(LA[0], 1);
  BAR; MFMA_Q(1, 0); BAR;
  MFMA_Q(1, 1);
  asm volatile("s_waitcnt vmcnt(0)");
  __builtin_amdgcn_sched_barrier(0);
  BAR;
  READS_A(LA[1], 0); READS_B01(LB[1]);
  WAITL8;
  BAR; MFMA_Q(0, 0); BAR;
  READS_B23(LB[1]);
  BAR; MFMA_Q(0, 1); BAR;
  READS_A(LA[1], 1);
  BAR; MFMA_Q(1, 0); BAR;
  MFMA_Q(1, 1);

#undef STG
#undef DSR0
#undef DSR
#undef READS_A
#undef READS_B01
#undef READS_B23
#undef WAITL8
#undef MFMA_Q
#undef BAR

  const int cr = (lane >> 4) * 4;
  const int cc = lane & 15;
  const int rowb = m0 + wm;
  const int bb_  = rowb >> 12;
  const int tb   = rowb & 4095;

  if (isScore) {
    // SC plane store: plane = qk*8+p, row (b*16+h), float4 over 4 consecutive t
#pragma unroll
    for (int i = 0; i < 8; ++i)
#pragma unroll
      for (int j = 0; j < 4; ++j) {
        const int col = wn + j * 16 + cc;            // [0,256)
        const int plane = ((col >> 7) << 3) | (col & 7);
        const int h = (col >> 3) & 15;
        float4 st = {acc[i][j][0], acc[i][j][1], acc[i][j][2], acc[i][j][3]};
        *(float4*)&SC[(size_t)plane * SCPL + ((size_t)(bb_ * NH + h)) * SEQ + tb + i * 16 + cr] = st;
      }
  } else {
    // v-plane scatter (head, d)
    const int ncol = n0 + wn;
    const int hh   = ncol >> 6;
    bf16* Cp = vOut + (size_t)(bb_ * NH + hh) * SEQ * DH;
#pragma unroll
    for (int i = 0; i < 8; ++i)
#pragma unroll
      for (int j = 0; j < 4; ++j)
#pragma unroll
        for (int r = 0; r < 4; ++r)
          Cp[(size_t)(tb + i * 16 + cr + r) * DH + (ncol & 63) + j * 16 + cc] = (bf16)acc[i][j][r];
  }
}

// ============================================================================
// attn_mid: scores from plane layout (16 coalesced 4B loads/thread), both
// softmaxes, PV partials (R7-verified phase 2).
// ============================================================================
__global__ __launch_bounds__(256)
void attn_mid(const float* __restrict__ SC, const bf16* __restrict__ v,
              bf16* __restrict__ P2,
              float* __restrict__ pm, float* __restrict__ pl,
              float* __restrict__ pva) {
  const int tc = blockIdx.x, bh = blockIdx.y;
  const int tid = threadIdx.x;
  const int t0 = tc * TCL;

  __shared__ float se[TCL][9];
  __shared__ float rm[4][8], rl[4][8];

  const float* scb = SC + (size_t)bh * SEQ + t0 + tid;
  float scq[8], sck[8];
#pragma unroll
  for (int p = 0; p < 8; ++p) {
    scq[p] = scb[(size_t)p * SCPL];
    sck[p] = scb[(size_t)(8 + p) * SCPL];
  }

  // P2: per-row softmax over p
  {
    float m = scq[0];
#pragma unroll
    for (int p = 1; p < 8; ++p) m = fmaxf(m, scq[p]);
    float wsum = 0.f, wgt[8];
#pragma unroll
    for (int p = 0; p < 8; ++p) { wgt[p] = __expf(scq[p] - m); wsum += wgt[p]; }
    float inv = 1.0f / wsum;
    int b = bh >> 4, h = bh & 15;
    bf16x8 o8;
#pragma unroll
    for (int p = 0; p < 8; ++p) o8[p] = (bf16)(wgt[p] * inv);
    *(bf16x8*)&P2[((size_t)(b * SEQ + t0 + tid)) * HP + h * 8] = o8;
  }

  // k path: chunk max
  float mx[8];
#pragma unroll
  for (int p = 0; p < 8; ++p) mx[p] = sck[p];
#pragma unroll
  for (int o = 32; o; o >>= 1)
#pragma unroll
    for (int p = 0; p < 8; ++p) mx[p] = fmaxf(mx[p], __shfl_xor(mx[p], o));
  if ((tid & 63) == 0)
#pragma unroll
    for (int p = 0; p < 8; ++p) rm[tid >> 6][p] = mx[p];
  __syncthreads();
  float m[8];
#pragma unroll
  for (int p = 0; p < 8; ++p)
    m[p] = fmaxf(fmaxf(rm[0][p], rm[1][p]), fmaxf(rm[2][p], rm[3][p]));

  float sl[8];
#pragma unroll
  for (int p = 0; p < 8; ++p) {
    float e = __expf(sck[p] - m[p]);
    se[tid][p] = e;
    sl[p] = e;
  }
#pragma unroll
  for (int o = 32; o; o >>= 1)
#pragma unroll
    for (int p = 0; p < 8; ++p) sl[p] += __shfl_xor(sl[p], o);
  if ((tid & 63) == 0)
#pragma unroll
    for (int p = 0; p < 8; ++p) rl[tid >> 6][p] = sl[p];
  __syncthreads();
  if (tid < 8) {
    float l = rl[0][tid] + rl[1][tid] + rl[2][tid] + rl[3][tid];
    pm[(size_t)(bh * TCH + tc) * 8 + tid] = m[tid];
    pl[(size_t)(bh * TCH + tc) * 8 + tid] = l;
  }
  __syncthreads();   // se complete for phase 2

  // phase 2: pva[p][d] = sum_t se[t][p]*v[t][d]
  const int lane = tid & 63;
  const int wv = tid >> 6;
  const int dg = lane & 7;
  const int to = lane >> 3;
  const int p0 = wv * 2;
  const bf16* vb = v + ((size_t)bh * SEQ + t0 + to) * DH + dg * 8;
  float a0[8] = {}, a1[8] = {};
  for (int tl = to; tl < TCL; tl += 8) {
    bf16x8 v8 = *(const bf16x8*)(vb + (size_t)(tl - to) * DH);
    float w0 = se[tl][p0];
    float w1 = se[tl][p0 + 1];
#pragma unroll
    for (int e = 0; e < 8; ++e) {
      float vf = (float)v8[e];
      a0[e] += w0 * vf;
      a1[e] += w1 * vf;
    }
  }
#pragma unroll
  for (int o = 8; o <= 32; o <<= 1) {
#pragma unroll
    for (int e = 0; e < 8; ++e) {
      a0[e] += __shfl_xor(a0[e], o);
      a1[e] += __shfl_xor(a1[e], o);
    }
  }
  if (to == 0) {
    float* o0 = pva + ((size_t)(bh * TCH + tc) * 8 + p0) * DH + dg * 8;
    float* o1 = o0 + DH;
#pragma unroll
    for (int e = 0; e < 8; ++e) { o0[e] = a0[e]; o1[e] = a1[e]; }
  }
}

// ---------------- combine chunk partials -> v_agent[bh][p][d] ----------------
__global__ void combine_vag(const float* __restrict__ pm, const float* __restrict__ pl,
                            const float* __restrict__ pva, float* __restrict__ vag) {
  int bh = blockIdx.x;
#pragma unroll
  for (int e = threadIdx.x; e < 512; e += 256) {
    int p = e >> 6, d = e & 63;
    float M = -1e30f;
#pragma unroll
    for (int tc = 0; tc < TCH; ++tc)
      M = fmaxf(M, pm[(size_t)(bh * TCH + tc) * 8 + p]);
    float L = 0.f, acc = 0.f;
#pragma unroll
    for (int tc = 0; tc < TCH; ++tc) {
      float w = __expf(pm[(size_t)(bh * TCH + tc) * 8 + p] - M);
      L   += w * pl[(size_t)(bh * TCH + tc) * 8 + p];
      acc += w * pva[((size_t)(bh * TCH + tc) * 8 + p) * DH + d];
    }
    vag[(size_t)bh * 512 + e] = acc / L;
  }
}

// ---- W2T[b][n][hp] = sum_d vag[b][hp][d] * WoT[n][h*64+d]  (bf16 out) ----
__global__ void w2_build(const float* __restrict__ vag, const bf16* __restrict__ WoT,
                         bf16* __restrict__ W2T) {
  int b = blockIdx.y;
  int n = blockIdx.x * 16 + (threadIdx.x & 15);
  int h = threadIdx.x >> 4;
  __shared__ float vg[128][65];
  for (int i = threadIdx.x; i < 128 * 64; i += 256)
    vg[i >> 6][i & 63] = vag[(size_t)b * 128 * 64 + i];
  __syncthreads();
  float acc[8] = {};
  const bf16* wrow = WoT + (size_t)n * DIMV + h * 64;
#pragma unroll
  for (int dv = 0; dv < 8; ++dv) {
    bf16x8 wv = *(const bf16x8*)(wrow + dv * 8);
#pragma unroll
    for (int e = 0; e < 8; ++e) {
      float wf = (float)wv[e];
      int d = dv * 8 + e;
#pragma unroll
      for (int p = 0; p < 8; ++p) acc[p] += vg[h * 8 + p][d] * wf;
    }
  }
  bf16x8 o;
#pragma unroll
  for (int p = 0; p < 8; ++p) o[p] = (bf16)acc[p];
  *(bf16x8*)&W2T[((size_t)b * DIMV + n) * HP + h * 8] = o;
}

// ============================================================================
// GEMM2: out = P2 @ W2T(batched)^T + bo.  256^2 tile, K=128.  Grid 256.
// ============================================================================
__global__ __launch_bounds__(512, 2)
void gemm2_256(const bf16* __restrict__ A, const bf16* __restrict__ B,
               float* __restrict__ Out, const float* __restrict__ bias) {
  constexpr int K2 = HP;   // 128

  __shared__ __align__(16) bf16 LA[2][2][8192];
  __shared__ __align__(16) bf16 LB[2][2][8192];

  const int tid  = threadIdx.x;
  const int w    = tid >> 6;
  const int lane = tid & 63;
  const int wm = (w >> 2) * 128;
  const int wn = (w & 3) * 64;

  const int bid = blockIdx.x;
  const int swz = (bid & 7) * 32 + (bid >> 3);
  const int m0 = (swz >> 2) * 256;
  const int n0 = (swz & 3) * 256;

  const int rT  = tid >> 3;
  const int csT = (((tid & 7) ^ (rT & 7)) << 3);
  const bf16* Ag = A + (size_t)(m0 + rT) * K2 + csT;
  const bf16* Bg = B + ((size_t)(m0 >> 12) * DIMV + n0 + rT) * K2 + csT;

  const int rA = lane & 15, C = lane >> 4, xr = rA & 7;
  const unsigned s0 = (unsigned)(((0 * 4 + C) ^ xr) << 4);
  const unsigned s1 = (unsigned)(((1 * 4 + C) ^ xr) << 4);
  const unsigned aoff = (unsigned)((wm + rA) << 7);
  const unsigned boff = (unsigned)((wn + rA) << 7);

  f32x4 acc[8][4] = {};
  u32x4 aR[4][2], bR[4][2];

#define STG(arr, Gp, half, kofs) do {                                         \
    const bf16* _s = (Gp) + (size_t)((half) * 128) * K2 + (kofs);             \
    char* _d = (char*)&arr[half][0] + (w << 10);                              \
    __builtin_amdgcn_global_load_lds(AS1(_s), AS3(_d), 16, 0, 0);             \
    __builtin_amdgcn_global_load_lds(AS1(_s + 64 * K2), AS3(_d + 8192), 16, 0, 0); \
  } while (0)

#define DSR0(d, p)    asm volatile("ds_read_b128 %0, %1" : "=v"(d) : "v"(p))
#define DSR(d, p, o)  asm volatile("ds_read_b128 %0, %1 offset:" o : "=v"(d) : "v"(p))

#define READS_A(LAb, qm) do {                                                 \
    lds_cp _p0 = (lds_cp)(const char*)&LAb[0][0] + aoff + s0 + (qm) * 8192;   \
    lds_cp _p1 = (lds_cp)(const char*)&LAb[0][0] + aoff + s1 + (qm) * 8192;   \
    DSR0(aR[0][0], _p0); DSR(aR[1][0], _p0, "2048");                          \
    DSR(aR[2][0], _p0, "4096"); DSR(aR[3][0], _p0, "6144");                   \
    DSR0(aR[0][1], _p1); DSR(aR[1][1], _p1, "2048");                          \
    DSR(aR[2][1], _p1, "4096"); DSR(aR[3][1], _p1, "6144");                   \
  } while (0)

#define READS_B01(LBb) do {                                                   \
    lds_cp _p0 = (lds_cp)(const char*)&LBb[0][0] + boff + s0;                 \
    lds_cp _p1 = (lds_cp)(const char*)&LBb[0][0] + boff + s1;                 \
    DSR0(bR[0][0], _p0); DSR(bR[1][0], _p0, "2048");                          \
    DSR0(bR[0][1], _p1); DSR(bR[1][1], _p1, "2048");                          \
  } while (0)

#define READS_B23(LBb) do {                                                   \
    lds_cp _p0 = (lds_cp)(const char*)&LBb[0][0] + boff + s0;                 \
    lds_cp _p1 = (lds_cp)(const char*)&LBb[0][0] + boff + s1;                 \
    DSR(bR[2][0], _p0, "4096"); DSR(bR[3][0], _p0, "6144");                   \
    DSR(bR[2][1], _p1, "4096"); DSR(bR[3][1], _p1, "6144");                   \
  } while (0)

#define WAITL8 do { asm volatile("s_waitcnt lgkmcnt(8)");                     \
                    __builtin_amdgcn_sched_barrier(0); } while (0)

#define MFMA_Q(qm, qn) do {                                                   \
    asm volatile("s_waitcnt lgkmcnt(0)");                                     \
    __builtin_amdgcn_sched_barrier(0);                                        \
    __builtin_amdgcn_s_setprio(1);                                            \
    _Pragma("unroll")                                                         \
    for (int il = 0; il < 4; ++il)                                            \
      _Pragma("unroll")                                                       \
      for (int jj = 0; jj < 2; ++jj) {                                        \
        f32x4& ac = acc[(qm) * 4 + il][(qn) * 2 + jj];                        \
        ac = __builtin_amdgcn_mfma_f32_16x16x32_bf16(                         \
            __builtin_bit_cast(bf16x8, aR[il][0]),                            \
            __builtin_bit_cast(bf16x8, bR[(qn) * 2 + jj][0]), ac, 0, 0, 0);   \
        ac = __builtin_amdgcn_mfma_f32_16x16x32_bf16(                         \
            __builtin_bit_cast(bf16x8, aR[il][1]),                            \
            __builtin_bit_cast(bf16x8, bR[(qn) * 2 + jj][1]), ac, 0, 0, 0);   \
      }                                                                       \
    __builtin_amdgcn_s_setprio(0);                                            \
    __builtin_amdgcn_sched_barrier(0);                                        \
  } while (0)

#define BAR __builtin_amdgcn_s_barrier()

  STG(LA[0], Ag, 0, 0); STG(LA[0], Ag, 1, 0);
  STG(LB[0], Bg, 0, 0); STG(LB[0], Bg, 1, 0);
  STG(LB[1], Bg, 0, 64); STG(LB[1], Bg, 1, 64);
  asm volatile("s_waitcnt vmcnt(4)");
  __builtin_amdgcn_sched_barrier(0);
  BAR;

  READS_A(LA[0], 0); READS_B01(LB[0]);
  STG(LA[1], Ag, 0, 64);
  WAITL8;
  BAR; MFMA_Q(0, 0); BAR;
  READS_B23(LB[0]);
  STG(LA[1], Ag, 1, 64);
  BAR; MFMA_Q(0, 1); BAR;
  READS_A(LA[0], 1);
  BAR; MFMA_Q(1, 0); BAR;
  MFMA_Q(1, 1);
  asm volatile("s_waitcnt vmcnt(0)");
  __builtin_amdgcn_sched_barrier(0);
  BAR;
  READS_A(LA[1], 0); READS_B01(LB[1]);
  WAITL8;
  BAR; MFMA_Q(0, 0); BAR;
  READS_B23(LB[1]);
  BAR; MFMA_Q(0, 1); BAR;
  READS_A(LA[1], 1);
  BAR; MFMA_Q(1, 0); BAR;
  MFMA_Q(1, 1);

#undef STG
#undef DSR0
#undef DSR
#undef READS_A
#undef READS_B01
#undef READS_B23
#undef WAITL8
#undef MFMA_Q
#undef BAR

  const int cr = (lane >> 4) * 4;
  const int cc = lane & 15;
  const int rowb = m0 + wm;
  float bb4[4];
#pragma unroll
  for (int j = 0; j < 4; ++j) bb4[j] = bias[n0 + wn + j * 16 + cc];
#pragma unroll
  for (int i = 0; i < 8; ++i)
#pragma unroll
    for (int j = 0; j < 4; ++j) {
      const int col = n0 + wn + j * 16 + cc;
#pragma unroll
      for (int r = 0; r < 4; ++r)
        Out[(size_t)(rowb + i * 16 + cr + r) * DIMV + col] = acc[i][j][r] + bb4[j];
    }
}

extern "C" void kernel_launch(void* const* d_in, const int* in_sizes, int n_in,
                              void* d_out, int out_size, void* d_ws, size_t ws_size,
                              hipStream_t stream) {
  const float* x    = (const float*)d_in[0];   // [4,4096,1024] fp32
  const float* Wqkv = (const float*)d_in[1];   // [1024,3072]   fp32
  const float* Wo   = (const float*)d_in[2];   // [1024,1024]   fp32
  const float* bo   = (const float*)d_in[3];   // [1024]        fp32
  float* out = (float*)d_out;                  // [4,4096,1024] fp32

  char* ws = (char*)d_ws;
  bf16*  WqkvT  = (bf16*)ws;                                 ws += (size_t)QKV_N * DIMV * 2;   // 6MB (only v rows written)
  bf16*  WoT    = (bf16*)ws;                                 ws += (size_t)DIMV * DIMV * 2;    // 2MB
  bf16*  vpl    = (bf16*)ws;                                 ws += (size_t)BH * SEQ * DH * 2;  // 32MB v plane
  char*  wsu    = ws;                                        ws += (size_t)M_TOTAL * DIMV * 2; // 32MB
  bf16*  xb     = (bf16*)wsu;
  bf16*  P2     = (bf16*)wsu;                                 // 4MB (after xb dead)
  bf16*  W2T    = (bf16*)(wsu + (size_t)M_TOTAL * HP * 2);    // 1MB
  float* SC     = (float*)ws;                                ws += (size_t)16 * SCPL * 4;      // 16MB scores (plane layout)
  bf16*  scw    = (bf16*)ws;                                 ws += (size_t)BATCH * 256 * DIMV * 2; // 2MB
  float* xpool  = (float*)ws;                                ws += 32 * DIMV * 4;              // 128KB
  float* agent_s= (float*)ws;                                ws += 32 * DIMV * 4;              // 128KB
  float* pm     = (float*)ws;                                ws += BH * TCH * 8 * 4;
  float* pl     = (float*)ws;                                ws += BH * TCH * 8 * 4;
  float* pva    = (float*)ws;                                ws += (size_t)BH * TCH * 8 * DH * 4;
  float* vag    = (float*)ws;                                ws += 512 * 64 * 4;

  // atomically-accumulated buffers -> zero first
  hipMemsetAsync(xpool, 0, 32 * DIMV * 4, stream);
  hipMemsetAsync(agent_s, 0, 32 * DIMV * 4, stream);

  // prep: convert x (8192) + Wqkv v-cols transpose (1024) + Wo transpose (1024)
  prep<<<10240, 256, 0, stream>>>(x, xb, Wqkv, WqkvT, Wo, WoT);

  // agent from pooled x (pool commutes with linear map)
  pool_x<<<256, 256, 0, stream>>>(xb, xpool);
  agent_build<<<128, 256, 0, stream>>>(xpool, Wqkv, agent_s);
  w2cat_build<<<512, 256, 0, stream>>>(agent_s, Wqkv, scw);

  // fused: v = x@Wv (256 tiles) + SC = x@scw (64 tiles, plane-layout stores)
  vscore_gemm<<<320, 512, 0, stream>>>(xb, WqkvT + (size_t)2048 * DIMV, scw, vpl, SC);

  // softmaxes + PV partials (P2 overwrites xb region AFTER xb's last use)
  attn_mid<<<dim3(TCH, BH), 256, 0, stream>>>(SC, vpl, P2, pm, pl, pva);

  combine_vag<<<BH, 256, 0, stream>>>(pm, pl, pva, vag);
  w2_build<<<dim3(DIMV / 16, BATCH), 256, 0, stream>>>(vag, WoT, W2T);

  // out = P2 @ W2T(batched) + bo
  gemm2_256<<<256, 512, 0, stream>>>(P2, W2T, out, bo);
}